// Round 10
// baseline (353.319 us; speedup 1.0000x reference)
//
#include <hip/hip_runtime.h>

#define NC 100000
#define NF 400000
#define NE 1600000
#define C  64

// ============================================================================
// v10 (resubmit; round-9 bench was an infra failure, kernel never ran)
//  = v9 + (1) 8-wide feature-load batches in both sortgathers (round-8
// counters: sgC 3.1 TB/s vs sgF 3.95 TB/s on the same kernel shape => the
// deg-16 coarse inner loop's 4 serial 4-load iterations are latency-bound;
// doubling loads-in-flight raises effective BW; VGPR 20 -> ~60, still under
// the (1024,8) 64-reg cap), and (2) inv-scatter folded into the partition
// dispatch as extra blocks (k_inv was a ~10-25us serial dispatch; cursor
// zeroing moves to a 4KB memset).
// ============================================================================

#define NSUB 512                // buckets per phase
#define CAPB 4096               // records per bucket (mean ~3130)
#define SUBC 196                // dst nodes per coarse bucket
#define SUBF 782                // dst nodes per fine bucket
#define NTILES ((NE + 4095) / 4096)   // 391
#define NINVB  ((NC + 255) / 256)     // 391 inv-scatter blocks

template<int SUBDIV>
__device__ __forceinline__ void part_tile(
    const int* __restrict__ dst, const int* __restrict__ src,
    const float* __restrict__ w, int* __restrict__ cur, int2* __restrict__ buf,
    int tile, int* lcnt)
{
    int tid = threadIdx.x;
    int e0 = tile * 4096;
    for (int i = tid; i < NSUB; i += 256) lcnt[i] = 0;
    __syncthreads();
    int rb[16]; int2 rv[16];
    #pragma unroll
    for (int i = 0; i < 16; ++i) {
        int e = e0 + i * 256 + tid;
        if (e < NE) {
            int d  = dst[e];
            int bk = d / SUBDIV;
            rb[i]  = bk;
            rv[i]  = make_int2(((d - bk * SUBDIV) << 17) | src[e],
                               __float_as_int(w[e]));
            atomicAdd(&lcnt[bk], 1);
        } else rb[i] = -1;
    }
    __syncthreads();
    for (int i = tid; i < NSUB; i += 256)
        lcnt[i] = i * CAPB + atomicAdd(&cur[i], lcnt[i]);
    __syncthreads();
    #pragma unroll
    for (int i = 0; i < 16; ++i) {
        if (rb[i] >= 0) {
            int p = atomicAdd(&lcnt[rb[i]], 1);
            if (p < (rb[i] + 1) * CAPB) buf[p] = rv[i];   // overflow guard
        }
    }
}

// blocks [0,391): coarse partition; [391,782): fine partition;
// [782,1173): inv scatter. Branch is block-uniform.
__global__ __launch_bounds__(256) void k_mega(
    const int* __restrict__ cd, const int* __restrict__ cs,
    const float* __restrict__ cw,
    const int* __restrict__ pd, const int* __restrict__ ps,
    const float* __restrict__ pw,
    const int* __restrict__ fwd, int* __restrict__ inv,
    int* __restrict__ curC, int* __restrict__ curF,
    int2* __restrict__ bufC, int2* __restrict__ bufF)
{
    __shared__ int lcnt[NSUB];
    int bx = blockIdx.x;
    if (bx < NTILES) {
        part_tile<SUBC>(cd, cs, cw, curC, bufC, bx, lcnt);
    } else if (bx < 2 * NTILES) {
        part_tile<SUBF>(pd, ps, pw, curF, bufF, bx - NTILES, lcnt);
    } else {
        int i = (bx - 2 * NTILES) * 256 + threadIdx.x;
        if (i < NC) inv[fwd[i]] = i;
    }
}

// Block = bucket. LDS sort + direct gather, 8-wide load batches.
template<int SUBDIV, int NTOT, bool FINE>
__global__ __launch_bounds__(1024, 8) void k_sortgather(
    const int2* __restrict__ buf, const int* __restrict__ cur,
    const float* __restrict__ feat,      // x (coarse) or h (fine)
    const int* __restrict__ inv,         // fine only
    float* __restrict__ outp)            // h/agg (coarse) or out (fine)
{
    __shared__ int2 srt[CAPB];           // 32 KB sorted records
    __shared__ int  cnt[SUBDIV];         // per-node cursor/end
    __shared__ int  scn[1024];
    int tid = threadIdx.x;
    int blk = blockIdx.x;
    int nodeLo = blk * SUBDIV;
    int nNodes = min(SUBDIV, NTOT - nodeLo);
    if (nNodes <= 0) return;             // uniform per block
    int lo = blk * CAPB;
    int n  = min(cur[blk], CAPB);        // cur holds the count

    for (int i = tid; i < SUBDIV; i += 1024) cnt[i] = 0;
    __syncthreads();

    // ---- load records into regs + LDS hist ----
    int2 r[CAPB / 1024];
    #pragma unroll
    for (int k = 0; k < CAPB / 1024; ++k) {
        int i = k * 1024 + tid;
        if (i < n) { r[k] = buf[lo + i]; atomicAdd(&cnt[r[k].x >> 17], 1); }
        else r[k].x = -1;
    }
    __syncthreads();

    // ---- exclusive scan of node counts (SUBDIV <= 1024) ----
    int v = (tid < SUBDIV) ? cnt[tid] : 0;
    scn[tid] = v; __syncthreads();
    for (int off = 1; off < 1024; off <<= 1) {
        int x = scn[tid];
        if (tid >= off) x += scn[tid - off];
        __syncthreads(); scn[tid] = x; __syncthreads();
    }
    if (tid < SUBDIV) cnt[tid] = scn[tid] - v;   // exclusive -> cursor
    __syncthreads();

    // ---- place into LDS sorted array ----
    #pragma unroll
    for (int k = 0; k < CAPB / 1024; ++k) {
        if (r[k].x >= 0) {
            int p = atomicAdd(&cnt[r[k].x >> 17], 1);
            srt[p] = r[k];
        }
    }
    __syncthreads();                     // cnt[dl] now = inclusive end

    // ---- gather: one 16-lane quadrant per node, 8 loads in flight ----
    int qd = tid >> 4;                   // 0..63
    int c4 = (tid & 15) << 2;
    for (int nl = qd; nl < nNodes; nl += 64) {
        int node = nodeLo + nl;
        if (FINE) {
            int iv = inv[node];
            if (iv >= 0) {               // injection: copy h row
                float4 vv = *(const float4*)(feat + (size_t)iv * C + c4);
                *(float4*)(outp + (size_t)node * C + c4) = vv;
                continue;
            }
        }
        int s = (nl == 0) ? 0 : cnt[nl - 1];
        int e = cnt[nl];
        float ax = 0.f, ay = 0.f, az = 0.f, aw = 0.f;
        for (int j = s; j < e; j += 8) {
            int2 q0 = srt[j];
            int2 q1 = (j + 1 < e) ? srt[j + 1] : make_int2(0, 0);
            int2 q2 = (j + 2 < e) ? srt[j + 2] : make_int2(0, 0);
            int2 q3 = (j + 3 < e) ? srt[j + 3] : make_int2(0, 0);
            int2 q4 = (j + 4 < e) ? srt[j + 4] : make_int2(0, 0);
            int2 q5 = (j + 5 < e) ? srt[j + 5] : make_int2(0, 0);
            int2 q6 = (j + 6 < e) ? srt[j + 6] : make_int2(0, 0);
            int2 q7 = (j + 7 < e) ? srt[j + 7] : make_int2(0, 0);
            float4 v0 = *(const float4*)(feat + (size_t)(q0.x & 0x1FFFF) * C + c4);
            float4 v1 = *(const float4*)(feat + (size_t)(q1.x & 0x1FFFF) * C + c4);
            float4 v2 = *(const float4*)(feat + (size_t)(q2.x & 0x1FFFF) * C + c4);
            float4 v3 = *(const float4*)(feat + (size_t)(q3.x & 0x1FFFF) * C + c4);
            float4 v4 = *(const float4*)(feat + (size_t)(q4.x & 0x1FFFF) * C + c4);
            float4 v5 = *(const float4*)(feat + (size_t)(q5.x & 0x1FFFF) * C + c4);
            float4 v6 = *(const float4*)(feat + (size_t)(q6.x & 0x1FFFF) * C + c4);
            float4 v7 = *(const float4*)(feat + (size_t)(q7.x & 0x1FFFF) * C + c4);
            float w0 = __int_as_float(q0.y), w1 = __int_as_float(q1.y);
            float w2 = __int_as_float(q2.y), w3 = __int_as_float(q3.y);
            float w4 = __int_as_float(q4.y), w5 = __int_as_float(q5.y);
            float w6 = __int_as_float(q6.y), w7 = __int_as_float(q7.y);
            ax = fmaf(w0, v0.x, ax); ay = fmaf(w0, v0.y, ay);
            az = fmaf(w0, v0.z, az); aw = fmaf(w0, v0.w, aw);
            ax = fmaf(w1, v1.x, ax); ay = fmaf(w1, v1.y, ay);
            az = fmaf(w1, v1.z, az); aw = fmaf(w1, v1.w, aw);
            ax = fmaf(w2, v2.x, ax); ay = fmaf(w2, v2.y, ay);
            az = fmaf(w2, v2.z, az); aw = fmaf(w2, v2.w, aw);
            ax = fmaf(w3, v3.x, ax); ay = fmaf(w3, v3.y, ay);
            az = fmaf(w3, v3.z, az); aw = fmaf(w3, v3.w, aw);
            ax = fmaf(w4, v4.x, ax); ay = fmaf(w4, v4.y, ay);
            az = fmaf(w4, v4.z, az); aw = fmaf(w4, v4.w, aw);
            ax = fmaf(w5, v5.x, ax); ay = fmaf(w5, v5.y, ay);
            az = fmaf(w5, v5.z, az); aw = fmaf(w5, v5.w, aw);
            ax = fmaf(w6, v6.x, ax); ay = fmaf(w6, v6.y, ay);
            az = fmaf(w6, v6.z, az); aw = fmaf(w6, v6.w, aw);
            ax = fmaf(w7, v7.x, ax); ay = fmaf(w7, v7.y, ay);
            az = fmaf(w7, v7.z, az); aw = fmaf(w7, v7.w, aw);
        }
        *(float4*)(outp + (size_t)node * C + c4) = make_float4(ax, ay, az, aw);
    }
}

// Tiled GEMM: h[64 rows] = h[64 rows] @ W + b, x-tile + W in LDS. (exact v9)
__global__ __launch_bounds__(256) void k_gemm_tile(
    float* __restrict__ h, const float* __restrict__ W,
    const float* __restrict__ bias)
{
    __shared__ float xs[64][68];
    __shared__ float ws[64][68];
    __shared__ float bs[64];
    int tid = threadIdx.x;
    int r0 = blockIdx.x * 64;

    for (int i = tid; i < 1024; i += 256) {
        int k = i >> 4, c = (i & 15) << 2;
        *(float4*)&ws[k][c] = ((const float4*)W)[i];
        int r = r0 + k;
        float4 xv = (r < NC) ? *(const float4*)(h + (size_t)r * C + c)
                             : make_float4(0, 0, 0, 0);
        *(float4*)&xs[k][c] = xv;
    }
    if (tid < 64) bs[tid] = bias[tid];
    __syncthreads();

    int tr = tid >> 4;
    int tc = tid & 15;
    float4 a0 = make_float4(0, 0, 0, 0), a1 = a0, a2 = a0, a3 = a0;
    #pragma unroll
    for (int kk = 0; kk < 16; ++kk) {
        int k = kk << 2;
        float4 x0 = *(const float4*)&xs[tr * 4 + 0][k];
        float4 x1 = *(const float4*)&xs[tr * 4 + 1][k];
        float4 x2 = *(const float4*)&xs[tr * 4 + 2][k];
        float4 x3 = *(const float4*)&xs[tr * 4 + 3][k];
        float4 w0 = *(const float4*)&ws[k + 0][tc * 4];
        float4 w1 = *(const float4*)&ws[k + 1][tc * 4];
        float4 w2 = *(const float4*)&ws[k + 2][tc * 4];
        float4 w3 = *(const float4*)&ws[k + 3][tc * 4];
        a0.x = fmaf(x0.x, w0.x, a0.x); a0.y = fmaf(x0.x, w0.y, a0.y);
        a0.z = fmaf(x0.x, w0.z, a0.z); a0.w = fmaf(x0.x, w0.w, a0.w);
        a0.x = fmaf(x0.y, w1.x, a0.x); a0.y = fmaf(x0.y, w1.y, a0.y);
        a0.z = fmaf(x0.y, w1.z, a0.z); a0.w = fmaf(x0.y, w1.w, a0.w);
        a0.x = fmaf(x0.z, w2.x, a0.x); a0.y = fmaf(x0.z, w2.y, a0.y);
        a0.z = fmaf(x0.z, w2.z, a0.z); a0.w = fmaf(x0.z, w2.w, a0.w);
        a0.x = fmaf(x0.w, w3.x, a0.x); a0.y = fmaf(x0.w, w3.y, a0.y);
        a0.z = fmaf(x0.w, w3.z, a0.z); a0.w = fmaf(x0.w, w3.w, a0.w);
        a1.x = fmaf(x1.x, w0.x, a1.x); a1.y = fmaf(x1.x, w0.y, a1.y);
        a1.z = fmaf(x1.x, w0.z, a1.z); a1.w = fmaf(x1.x, w0.w, a1.w);
        a1.x = fmaf(x1.y, w1.x, a1.x); a1.y = fmaf(x1.y, w1.y, a1.y);
        a1.z = fmaf(x1.y, w1.z, a1.z); a1.w = fmaf(x1.y, w1.w, a1.w);
        a1.x = fmaf(x1.z, w2.x, a1.x); a1.y = fmaf(x1.z, w2.y, a1.y);
        a1.z = fmaf(x1.z, w2.z, a1.z); a1.w = fmaf(x1.z, w2.w, a1.w);
        a1.x = fmaf(x1.w, w3.x, a1.x); a1.y = fmaf(x1.w, w3.y, a1.y);
        a1.z = fmaf(x1.w, w3.z, a1.z); a1.w = fmaf(x1.w, w3.w, a1.w);
        a2.x = fmaf(x2.x, w0.x, a2.x); a2.y = fmaf(x2.x, w0.y, a2.y);
        a2.z = fmaf(x2.x, w0.z, a2.z); a2.w = fmaf(x2.x, w0.w, a2.w);
        a2.x = fmaf(x2.y, w1.x, a2.x); a2.y = fmaf(x2.y, w1.y, a2.y);
        a2.z = fmaf(x2.y, w1.z, a2.z); a2.w = fmaf(x2.y, w1.w, a2.w);
        a2.x = fmaf(x2.z, w2.x, a2.x); a2.y = fmaf(x2.z, w2.y, a2.y);
        a2.z = fmaf(x2.z, w2.z, a2.z); a2.w = fmaf(x2.z, w2.w, a2.w);
        a2.x = fmaf(x2.w, w3.x, a2.x); a2.y = fmaf(x2.w, w3.y, a2.y);
        a2.z = fmaf(x2.w, w3.z, a2.z); a2.w = fmaf(x2.w, w3.w, a2.w);
        a3.x = fmaf(x3.x, w0.x, a3.x); a3.y = fmaf(x3.x, w0.y, a3.y);
        a3.z = fmaf(x3.x, w0.z, a3.z); a3.w = fmaf(x3.x, w0.w, a3.w);
        a3.x = fmaf(x3.y, w1.x, a3.x); a3.y = fmaf(x3.y, w1.y, a3.y);
        a3.z = fmaf(x3.y, w1.z, a3.z); a3.w = fmaf(x3.y, w1.w, a3.w);
        a3.x = fmaf(x3.z, w2.x, a3.x); a3.y = fmaf(x3.z, w2.y, a3.y);
        a3.z = fmaf(x3.z, w2.z, a3.z); a3.w = fmaf(x3.z, w2.w, a3.w);
        a3.x = fmaf(x3.w, w3.x, a3.x); a3.y = fmaf(x3.w, w3.y, a3.y);
        a3.z = fmaf(x3.w, w3.z, a3.z); a3.w = fmaf(x3.w, w3.w, a3.w);
    }
    float4 bv = *(const float4*)&bs[tc * 4];
    a0.x += bv.x; a0.y += bv.y; a0.z += bv.z; a0.w += bv.w;
    a1.x += bv.x; a1.y += bv.y; a1.z += bv.z; a1.w += bv.w;
    a2.x += bv.x; a2.y += bv.y; a2.z += bv.z; a2.w += bv.w;
    a3.x += bv.x; a3.y += bv.y; a3.z += bv.z; a3.w += bv.w;
    int rb = r0 + tr * 4;
    if (rb + 0 < NC) *(float4*)(h + (size_t)(rb + 0) * C + tc * 4) = a0;
    if (rb + 1 < NC) *(float4*)(h + (size_t)(rb + 1) * C + tc * 4) = a1;
    if (rb + 2 < NC) *(float4*)(h + (size_t)(rb + 2) * C + tc * 4) = a2;
    if (rb + 3 < NC) *(float4*)(h + (size_t)(rb + 3) * C + tc * 4) = a3;
}

extern "C" void kernel_launch(void* const* d_in, const int* in_sizes, int n_in,
                              void* d_out, int out_size, void* d_ws, size_t ws_size,
                              hipStream_t stream) {
    const float* x    = (const float*)d_in[0];
    const float* W    = (const float*)d_in[1];
    const float* b    = (const float*)d_in[2];
    const int*   ei   = (const int*)d_in[3];   // [2,E]: src = ei, dst = ei+NE
    const float* ea   = (const float*)d_in[4];
    const int*   psrc = (const int*)d_in[5];
    const int*   pdst = (const int*)d_in[6];
    const float* pw   = (const float*)d_in[7];
    const int*   fwd  = (const int*)d_in[8];
    float* out = (float*)d_out;

    // Workspace (~60.8 MB): h | bufC | bufF | inv | curC+curF
    char* p = (char*)d_ws;
    float* h    = (float*)p;  p += (size_t)NC * C * sizeof(float);       // 25.6 MB
    int2*  bufC = (int2*)p;   p += (size_t)NSUB * CAPB * sizeof(int2);   // 16.8 MB
    int2*  bufF = (int2*)p;   p += (size_t)NSUB * CAPB * sizeof(int2);   // 16.8 MB
    int*   inv  = (int*)p;    p += (size_t)NF * sizeof(int);             // 1.6 MB
    int*   curC = (int*)p;    p += NSUB * sizeof(int);
    int*   curF = (int*)p;    p += NSUB * sizeof(int);

    // inv <- -1, cursors <- 0 (tiny async fills)
    hipMemsetAsync(inv, 0xFF, (size_t)NF * sizeof(int), stream);
    hipMemsetAsync(curC, 0, 2 * NSUB * sizeof(int), stream);

    // ---- both partitions + inv scatter in ONE dispatch ----
    k_mega<<<2 * NTILES + NINVB, 256, 0, stream>>>(
        ei + NE, ei, ea, pdst, psrc, pw, fwd, inv, curC, curF, bufC, bufF);

    // ---- coarse: fused sort+gather (agg -> h), then tiled GEMM ----
    k_sortgather<SUBC, NC, false><<<NSUB, 1024, 0, stream>>>(
        bufC, curC, x, nullptr, h);
    k_gemm_tile<<<(NC + 63) / 64, 256, 0, stream>>>(h, W, b);

    // ---- fine: fused sort+gather+inject -> out ----
    k_sortgather<SUBF, NF, true><<<NSUB, 1024, 0, stream>>>(
        bufF, curF, h, inv, out);
}